// Round 1
// baseline (286.179 us; speedup 1.0000x reference)
//
#include <hip/hip_runtime.h>

typedef _Float16 half4_t __attribute__((ext_vector_type(4)));
typedef _Float16 half8_t __attribute__((ext_vector_type(8)));
typedef float floatx4 __attribute__((ext_vector_type(4)));

constexpr int S_  = 4096;
constexpr int D_  = 64;
constexpr int NBH = 24;     // B*H
constexpr int BM  = 128;    // queries per block (4 waves x 32)
constexpr int BN  = 64;     // keys per iteration
constexpr int SK  = 72;     // K LDS row stride (elements, 16B-aligned rows)
constexpr int SV  = 68;     // V^T LDS row stride (elements, 8B-aligned rows)
constexpr float SC2 = 0.125f * 1.44269504088896340736f;  // scale * log2(e)

__global__ __launch_bounds__(256, 2) void fattn_kernel(
    const float* __restrict__ Q, const float* __restrict__ K,
    const float* __restrict__ V, float* __restrict__ O)
{
  __shared__ __align__(16) _Float16 Ks[64 * SK];
  __shared__ __align__(16) _Float16 Vs[64 * SV];

  const int tid  = threadIdx.x;
  const int lane = tid & 63;
  const int w    = tid >> 6;       // wave id 0..3
  const int g    = lane >> 4;      // quad 0..3
  const int m    = lane & 15;

  const int bid  = blockIdx.x;
  const int bh   = bid >> 5;       // S_/BM = 32 q-blocks per (b,h)
  const int qblk = bid & 31;
  const size_t base = (size_t)bh * S_ * D_;
  const int q0 = qblk * BM + w * 32;   // this wave's first query row

  // Q fragments: B-operand of S^T = K * Q^T.  [qt][ks], k = 8g+j+32ks, n = m
  half8_t qf[2][2];
#pragma unroll
  for (int qt = 0; qt < 2; ++qt)
#pragma unroll
    for (int ks = 0; ks < 2; ++ks) {
      const float4* qp = (const float4*)(Q + base + (size_t)(q0 + qt*16 + m) * D_ + 8*g + 32*ks);
      float4 a = qp[0], b = qp[1];
      half8_t v = { (_Float16)a.x,(_Float16)a.y,(_Float16)a.z,(_Float16)a.w,
                    (_Float16)b.x,(_Float16)b.y,(_Float16)b.z,(_Float16)b.w };
      qf[qt][ks] = v;
    }

  floatx4 oacc[2][4];
#pragma unroll
  for (int qt = 0; qt < 2; ++qt)
#pragma unroll
    for (int db = 0; db < 4; ++db) oacc[qt][db] = (floatx4){0.f,0.f,0.f,0.f};
  float mrow[2] = {-1e30f, -1e30f};
  float lrow[2] = {0.f, 0.f};

  const float* Kb = K + base;
  const float* Vb = V + base;

  for (int kt = 0; kt < S_ / BN; ++kt) {
    __syncthreads();
    // ---- stage K tile [key][d] (row-major, f16, stride SK) ----
    const float* Kt = Kb + (size_t)kt * BN * D_;
#pragma unroll
    for (int it = 0; it < 4; ++it) {
      int slot = tid + 256 * it;
      int key  = slot >> 4;
      int c4   = (slot & 15) << 2;
      float4 kv = *(const float4*)(Kt + (size_t)key * D_ + c4);
      half4_t hv = { (_Float16)kv.x,(_Float16)kv.y,(_Float16)kv.z,(_Float16)kv.w };
      *(half4_t*)(&Ks[key * SK + c4]) = hv;
    }
    // ---- stage V^T tile [d][key] (f16, stride SV); column-coalesced loads ----
    const float* Vtg = Vb + (size_t)kt * BN * D_;
    {
      const int dv  = lane;        // d = lane for every wave
      const int kq4 = w << 2;      // 4-key group per wave
#pragma unroll
      for (int it = 0; it < 4; ++it) {
        int kb = it * 16 + kq4;
        const float* vp = Vtg + (size_t)kb * D_ + dv;
        half4_t hv = { (_Float16)vp[0], (_Float16)vp[D_],
                       (_Float16)vp[2*D_], (_Float16)vp[3*D_] };
        *(half4_t*)(&Vs[dv * SV + kb]) = hv;
      }
    }
    __syncthreads();

    // ---- K fragments (A-operand of S^T): A[m'=key][k=d] ----
    half8_t kf[4][2];
#pragma unroll
    for (int nb = 0; nb < 4; ++nb)
#pragma unroll
      for (int ks = 0; ks < 2; ++ks)
        kf[nb][ks] = *(const half8_t*)(&Ks[(16*nb + m) * SK + 8*g + 32*ks]);

    // ---- V fragments (B-operand of PV, 16x16x16): B[k=key][n=d] ----
    half4_t vf[4][4];
#pragma unroll
    for (int nb = 0; nb < 4; ++nb)
#pragma unroll
      for (int db = 0; db < 4; ++db)
        vf[nb][db] = *(const half4_t*)(&Vs[(16*db + m) * SV + 16*nb + 4*g]);

#pragma unroll
    for (int qt = 0; qt < 2; ++qt) {
      // S^T = K * Q^T : lane(g,m) holds S^T[16nb+4g+r][query m]
      floatx4 sacc[4];
#pragma unroll
      for (int nb = 0; nb < 4; ++nb) sacc[nb] = (floatx4){0.f,0.f,0.f,0.f};
#pragma unroll
      for (int nb = 0; nb < 4; ++nb)
#pragma unroll
        for (int ks = 0; ks < 2; ++ks)
          sacc[nb] = __builtin_amdgcn_mfma_f32_16x16x32_f16(kf[nb][ks], qf[qt][ks], sacc[nb], 0, 0, 0);

      // ---- online softmax (per query row = m, spread over lanes m,m+16,m+32,m+48) ----
      float mx = sacc[0][0];
#pragma unroll
      for (int nb = 0; nb < 4; ++nb)
#pragma unroll
        for (int r = 0; r < 4; ++r) mx = fmaxf(mx, sacc[nb][r]);
      mx = fmaxf(mx, __shfl_xor(mx, 16));
      mx = fmaxf(mx, __shfl_xor(mx, 32));
      float mnew  = fmaxf(mrow[qt], mx);
      float alpha = __builtin_amdgcn_exp2f(SC2 * (mrow[qt] - mnew));
      mrow[qt] = mnew;

      // P in registers: already in A-layout of 16x16x16 MFMA (k = 4g+r per nb)
      half4_t pf[4];
      float rsum = 0.f;
#pragma unroll
      for (int nb = 0; nb < 4; ++nb) {
        float p0 = __builtin_amdgcn_exp2f(SC2 * (sacc[nb][0] - mnew));
        float p1 = __builtin_amdgcn_exp2f(SC2 * (sacc[nb][1] - mnew));
        float p2 = __builtin_amdgcn_exp2f(SC2 * (sacc[nb][2] - mnew));
        float p3 = __builtin_amdgcn_exp2f(SC2 * (sacc[nb][3] - mnew));
        rsum += p0 + p1 + p2 + p3;
        half4_t pv = { (_Float16)p0, (_Float16)p1, (_Float16)p2, (_Float16)p3 };
        pf[nb] = pv;
      }
      rsum += __shfl_xor(rsum, 16);
      rsum += __shfl_xor(rsum, 32);
      lrow[qt] = lrow[qt] * alpha + rsum;

      // broadcast alpha from softmax layout (row=m) to O layout (row=4g+r)
      floatx4 abc;
#pragma unroll
      for (int r = 0; r < 4; ++r) abc[r] = __shfl(alpha, (lane & 48) + 4*g + r);
#pragma unroll
      for (int db = 0; db < 4; ++db) oacc[qt][db] *= abc;

      // O += P * V  (16x16x16 f16 MFMA; C row = 4g+r = query, col = 16db+m = d)
#pragma unroll
      for (int nb = 0; nb < 4; ++nb)
#pragma unroll
        for (int db = 0; db < 4; ++db)
          oacc[qt][db] = __builtin_amdgcn_mfma_f32_16x16x16f16(pf[nb], vf[nb][db], oacc[qt][db], 0, 0, 0);
    }
  }

  // ---- epilogue: normalize by l and store ----
#pragma unroll
  for (int qt = 0; qt < 2; ++qt) {
    floatx4 linv;
#pragma unroll
    for (int r = 0; r < 4; ++r)
      linv[r] = 1.0f / __shfl(lrow[qt], (lane & 48) + 4*g + r);
    float* Op = O + base + (size_t)(q0 + qt*16) * D_;
#pragma unroll
    for (int db = 0; db < 4; ++db)
#pragma unroll
      for (int r = 0; r < 4; ++r)
        Op[(size_t)(4*g + r) * D_ + 16*db + m] = oacc[qt][db][r] * linv[r];
  }
}

extern "C" void kernel_launch(void* const* d_in, const int* in_sizes, int n_in,
                              void* d_out, int out_size, void* d_ws, size_t ws_size,
                              hipStream_t stream) {
  const float* Q = (const float*)d_in[0];
  const float* K = (const float*)d_in[1];
  const float* V = (const float*)d_in[2];
  // d_in[3] = attn_mask (unused by reference forward)
  float* Out = (float*)d_out;

  dim3 grid(NBH * (S_ / BM));   // 24 * 32 = 768 blocks
  dim3 block(256);
  fattn_kernel<<<grid, block, 0, stream>>>(Q, K, V, Out);
}